// Round 4
// baseline (273.310 us; speedup 1.0000x reference)
//
#include <hip/hip_runtime.h>

// Problem constants
#define B_    64
#define C_    3
#define H_    384
#define W_    384
#define P_    16
#define E_    768
#define N_    576                 // patches per image
#define M_    (B_ * N_)           // 36864 total patches
#define K_    (C_ * P_ * P_)      // 768 reduction dim

// GEMM tiling: 128m x 256e x 32k, 512 threads (8 waves = 2x4 of 64x64)
#define BM    128
#define BN    256
#define BK    32

typedef __attribute__((ext_vector_type(8))) short  short8;   // bf16x8 MFMA operand
typedef __attribute__((ext_vector_type(4))) float  f32x4;    // MFMA accumulator

// round-to-nearest-even f32 -> bf16 bits
__device__ __forceinline__ unsigned short f2bf(float f) {
    unsigned int u = __float_as_uint(f);
    u += 0x7FFFu + ((u >> 16) & 1u);
    return (unsigned short)(u >> 16);
}

// async global->LDS, 16B per lane (global_load_lds_dwordx4)
__device__ __forceinline__ void gload_lds16(const void* g, void* l) {
    __builtin_amdgcn_global_load_lds(
        (const __attribute__((address_space(1))) unsigned int*)g,
        (__attribute__((address_space(3))) unsigned int*)l,
        16, 0, 0);
}

// ---------------------------------------------------------------------------
// Phase 1: gather patches -> contiguous bf16 A[M][768] in workspace.
// ---------------------------------------------------------------------------
__global__ __launch_bounds__(256)
void gather_kernel(const float* __restrict__ x,
                   const int*   __restrict__ ys,
                   const int*   __restrict__ xs,
                   unsigned short* __restrict__ Abf)
{
    const unsigned g = blockIdx.x * 256 + threadIdx.x;   // < M_*192
    const unsigned patch = g / 192u;
    const unsigned r  = g - patch * 192u;                // 0..191
    const unsigned c  = r >> 6;                          // channel 0..2
    const unsigned r2 = r & 63u;
    const unsigned py = r2 >> 2;                         // row in patch 0..15
    const unsigned q  = r2 & 3u;                         // 4-float quarter

    const unsigned bimg = patch / (unsigned)N_;
    const int y  = ys[patch];
    const int xx = xs[patch];

    const float* src = x + (size_t)bimg * (C_ * H_ * W_)
                         + (size_t)c * (H_ * W_)
                         + (size_t)(y + py) * W_ + xx + q * 4;

    uint2 pk;
    pk.x = (unsigned)f2bf(src[0]) | ((unsigned)f2bf(src[1]) << 16);
    pk.y = (unsigned)f2bf(src[2]) | ((unsigned)f2bf(src[3]) << 16);
    *(uint2*)(Abf + (size_t)g * 4) = pk;    // dest offset = g*4 elems
}

// Phase 1b: w [E][K] fp32 -> bf16 (B^T layout already)
__global__ __launch_bounds__(256)
void wconv_kernel(const float* __restrict__ w, unsigned short* __restrict__ Wb)
{
    const unsigned g = blockIdx.x * 256 + threadIdx.x;   // < E_*K_/4
    float4 f = ((const float4*)w)[g];
    uint2 pk;
    pk.x = (unsigned)f2bf(f.x) | ((unsigned)f2bf(f.y) << 16);
    pk.y = (unsigned)f2bf(f.z) | ((unsigned)f2bf(f.w) << 16);
    *(uint2*)(Wb + (size_t)g * 4) = pk;
}

// ---------------------------------------------------------------------------
// Phase 2: GEMM. A[M,768] bf16, B=Wb[E,768] bf16 (B^T), out fp32 + bias.
// 128x256x32 tile, 512 threads = 8 waves (2x4 of 64x64 subtiles).
// global_load_lds width-16 staging; XCD swizzle keeps the 3 e-tile sharers
// of an A-slab consecutive + same (b&7) so slab re-reads hit one L2.
// ---------------------------------------------------------------------------
__global__ __launch_bounds__(512, 4)
void gemm_bf16(const unsigned short* __restrict__ A,
               const unsigned short* __restrict__ Wb,
               const float* __restrict__ bias,
               float*       __restrict__ out)
{
    __shared__ unsigned short Asm[BM * BK];   //  8 KB
    __shared__ unsigned short Bsm[BN * BK];   // 16 KB

    const int t    = threadIdx.x;
    const int wave = t >> 6;                  // 0..7
    const int lane = t & 63;

    // XCD-aware swizzle: 864 blocks = 8 xcd-groups x 36 m-tiles x 3 e-tiles
    const int b   = blockIdx.x;
    const int xcd = b & 7;
    const int idx = b >> 3;                   // 0..107
    const int mt  = xcd * 36 + idx / 3;       // m-tile 0..287
    const int et  = idx % 3;                  // e-tile 0..2
    const int m0  = mt * BM;
    const int e0  = et * BN;

    // staging: per global_load_lds, one wave covers 16 rows (lane>>2) with
    // 16B chunks (lane&3). 8 waves/slot = 128 rows. A: 1 slot; B: 2 slots.
    const int srow = wave * 16 + (lane >> 2); // 0..127
    const int scol = (lane & 3) * 8;          // bf16 elem col
    const unsigned short* Ag = A  + (size_t)(m0 + srow) * K_ + scol;
    const unsigned short* Bg0 = Wb + (size_t)(e0 + srow) * K_ + scol;
    const unsigned short* Bg1 = Wb + (size_t)(e0 + 128 + srow) * K_ + scol;
    unsigned short* Al  = &Asm[srow * BK + scol];         // wavebase + lane*16B
    unsigned short* Bl0 = &Bsm[srow * BK + scol];
    unsigned short* Bl1 = &Bsm[(128 + srow) * BK + scol];

    // compute roles: wave (wr,wc) in 2x4 grid of 64x64
    const int wr   = (wave >> 2) * 64;
    const int wc   = (wave & 3) * 64;
    const int lm   = lane & 15;
    const int quad = lane >> 4;

    f32x4 acc[4][4];
#pragma unroll
    for (int i = 0; i < 4; ++i)
#pragma unroll
        for (int j = 0; j < 4; ++j)
            acc[i][j] = (f32x4){0.f, 0.f, 0.f, 0.f};

#pragma unroll 1
    for (int it = 0; it < K_ / BK; ++it) {
        const int ko = it * BK;
        gload_lds16(Ag  + ko, Al);
        gload_lds16(Bg0 + ko, Bl0);
        gload_lds16(Bg1 + ko, Bl1);

        __syncthreads();   // drains vmcnt before LDS use

        short8 af[4], bfr[4];
#pragma unroll
        for (int i = 0; i < 4; ++i)
            af[i] = *(const short8*)&Asm[(wr + i * 16 + lm) * BK + quad * 8];
#pragma unroll
        for (int j = 0; j < 4; ++j)
            bfr[j] = *(const short8*)&Bsm[(wc + j * 16 + lm) * BK + quad * 8];

#pragma unroll
        for (int i = 0; i < 4; ++i)
#pragma unroll
            for (int j = 0; j < 4; ++j)
                acc[i][j] = __builtin_amdgcn_mfma_f32_16x16x32_bf16(af[i], bfr[j], acc[i][j], 0, 0, 0);

        __syncthreads();
    }

    // epilogue: C/D layout col=lane&15, row=quad*4+reg (m89-verified)
    float bv[4];
#pragma unroll
    for (int j = 0; j < 4; ++j) bv[j] = bias[e0 + wc + j * 16 + lm];

#pragma unroll
    for (int i = 0; i < 4; ++i) {
#pragma unroll
        for (int j = 0; j < 4; ++j) {
            const int eo = e0 + wc + j * 16 + lm;
#pragma unroll
            for (int r = 0; r < 4; ++r) {
                const int mo = m0 + wr + i * 16 + quad * 4 + r;
                out[(size_t)mo * E_ + eo] = acc[i][j][r] + bv[j];
            }
        }
    }
}

__global__ void pos_kernel(const int* __restrict__ ys, const int* __restrict__ xs,
                           float* __restrict__ outp)
{
    int i = blockIdx.x * blockDim.x + threadIdx.x;
    if (i < M_) {
        outp[2 * i]     = (float)ys[i];
        outp[2 * i + 1] = (float)xs[i];
    }
}

extern "C" void kernel_launch(void* const* d_in, const int* in_sizes, int n_in,
                              void* d_out, int out_size, void* d_ws, size_t ws_size,
                              hipStream_t stream)
{
    const float* x    = (const float*)d_in[0];
    const int*   ys   = (const int*)d_in[1];
    const int*   xs   = (const int*)d_in[2];
    const float* w    = (const float*)d_in[3];
    const float* bias = (const float*)d_in[4];
    float* out = (float*)d_out;

    // workspace layout: A_bf16 [M][768] then W_bf16 [E][768]
    unsigned short* Abf = (unsigned short*)d_ws;
    unsigned short* Wb  = Abf + (size_t)M_ * K_;

    gather_kernel<<<(M_ * 192) / 256, 256, 0, stream>>>(x, ys, xs, Abf);
    wconv_kernel<<<(E_ * K_ / 4) / 256, 256, 0, stream>>>(w, Wb);

    gemm_bf16<<<(M_ / BM) * (E_ / BN), 512, 0, stream>>>(Abf, Wb, bias, out);

    float* outp = out + (size_t)M_ * E_;
    pos_kernel<<<(M_ + 255) / 256, 256, 0, stream>>>(ys, xs, outp);
}